// Round 2
// baseline (257.919 us; speedup 1.0000x reference)
//
#include <hip/hip_runtime.h>
#include <stdint.h>

#define EMB 512
#define THREE_E 1536
#define SL 16384
#define K_DIM 512

typedef unsigned short ushort;
typedef short bf16x8 __attribute__((ext_vector_type(8)));
typedef float f32x4 __attribute__((ext_vector_type(4)));

__device__ __forceinline__ ushort f2bf(float f) {
  unsigned u = __float_as_uint(f);
  u += 0x7fffu + ((u >> 16) & 1u);
  return (ushort)(u >> 16);
}
__device__ __forceinline__ float bf2f(ushort s) {
  return __uint_as_float((unsigned)s << 16);
}

// async global->LDS, 16 B per lane; lds arg must be the wave-uniform base.
__device__ __forceinline__ void async16(const ushort* g, ushort* l) {
  __builtin_amdgcn_global_load_lds(
      (const __attribute__((address_space(1))) unsigned int*)g,
      (__attribute__((address_space(3))) unsigned int*)l, 16, 0, 0);
}

// ---------------- W fp32 -> bf16 ----------------
__global__ __launch_bounds__(256) void wconv(const float* __restrict__ W,
                                             ushort* __restrict__ Wb) {
  int i = blockIdx.x * 256 + threadIdx.x;
  float4 f = ((const float4*)W)[i];
  uint2 o;
  o.x = (unsigned)f2bf(f.x) | ((unsigned)f2bf(f.y) << 16);
  o.y = (unsigned)f2bf(f.z) | ((unsigned)f2bf(f.w) << 16);
  ((uint2*)Wb)[i] = o;
}

// ---------------- x [B,E,S,L] fp32 -> xT [B, S*L, E] bf16 (vectorized) ----------------
__global__ __launch_bounds__(256) void xpose(const float* __restrict__ x,
                                             ushort* __restrict__ xT) {
  __shared__ ushort t[64][68];  // 68-pad: 8B-aligned rows, modest conflict on column reads
  int b = blockIdx.z;
  int i0 = blockIdx.y * 64;
  int n0 = blockIdx.x * 64;
  int tid = threadIdx.x;
  const float* xp = x + ((size_t)(b * EMB + i0)) * SL + n0;
  #pragma unroll
  for (int it = 0; it < 4; it++) {
    int f = it * 256 + tid;
    int r = f >> 4, c4 = (f & 15) * 4;
    float4 v = *(const float4*)&xp[(size_t)r * SL + c4];
    uint2 p;
    p.x = (unsigned)f2bf(v.x) | ((unsigned)f2bf(v.y) << 16);
    p.y = (unsigned)f2bf(v.z) | ((unsigned)f2bf(v.w) << 16);
    *(uint2*)&t[r][c4] = p;
  }
  __syncthreads();
  ushort* op = xT + ((size_t)(b * SL + n0)) * EMB + i0;
  #pragma unroll
  for (int it = 0; it < 4; it++) {
    int u = it * 256 + tid;
    int n = u >> 4, i4 = (u & 15) * 4;
    uint2 p;
    ushort* ps = (ushort*)&p;
    #pragma unroll
    for (int j = 0; j < 4; j++) ps[j] = t[i4 + j][n];
    *(uint2*)&op[(size_t)n * EMB + i4] = p;
  }
}

// ---------------- QKV GEMM: 128x128 tile, BK=32, dbuf, counted vmcnt, 3 blocks/CU ----------------
// LDS per buffer: A/B tiles packed as [64 rows][64 elem] (two n-rows of 32-k per LDS row),
// chunk-XOR-8 swizzled exactly like the proven round-0 layout. 4x8KB buffers = 32 KB; epilogue
// scratch (34816 B) bounds the block. 256 thr, per-wave 64x64 -> acc 64 AGPR, ~160 regs/wave
// -> 12 waves/CU = 3 blocks: cross-block overlap hides stage latency + store drain.
__global__ __launch_bounds__(256, 3) void qkv_gemm(const ushort* __restrict__ Wb,
                                                   const ushort* __restrict__ xT,
                                                   const float* __restrict__ bias,
                                                   ushort* __restrict__ rowQ) {
  __shared__ __align__(16) char sm[34816];
  ushort* const A0 = (ushort*)sm;
  ushort* const B0 = (ushort*)(sm + 8192);
  ushort* const A1 = (ushort*)(sm + 16384);
  ushort* const B1 = (ushort*)(sm + 24576);
  const int tid = threadIdx.x;
  const int b = blockIdx.z;
  const int m0 = blockIdx.x * 128;  // x = m so the 12 m-blocks per n-panel run consecutively
  const int n0 = blockIdx.y * 128;
  const int lane = tid & 63;
  const int w = tid >> 6;
  const int wr = (w >> 1) * 64;
  const int wc = (w & 1) * 64;
  const int l15 = lane & 15;
  const int quad = lane >> 4;
  const int hn = l15 & 1;  // n-parity of this lane's fragment rows
  const int r0s = w * 8 + (lane >> 3);
  const int cs = lane & 7;
  const ushort* Ag = Wb + (size_t)m0 * K_DIM;
  const ushort* Bg = xT + ((size_t)b * SL + n0) * K_DIM;
  f32x4 acc[4][4] = {};

// stage one 128x32 K-slab (8 KB) packed as [64][64]: LDS flat slot (row,c) holds logical
// (n = 2*row + (q>>2), k-chunk = q&3) with q = c ^ (row&7). Linear LDS dest, inv-swz source.
#define STG32(gb, lb)                                                     \
  {                                                                       \
    _Pragma("unroll") for (int j = 0; j < 2; j++) {                       \
      int row = j * 32 + r0s;                                             \
      int q = cs ^ (row & 7);                                             \
      int n = 2 * row + (q >> 2);                                         \
      async16((gb) + (size_t)n * K_DIM + (q & 3) * 8,                     \
              (lb) + j * 2048 + w * 512);                                 \
    }                                                                     \
  }

#define FRAGS(AP, BP)                                                     \
  _Pragma("unroll") for (int mt = 0; mt < 4; mt++) {                      \
    int n = wr + mt * 16 + l15;                                           \
    int R = n >> 1;                                                       \
    av[mt] = *(const bf16x8*)&(AP)[R * 64 + (((quad | (hn << 2)) ^ (R & 7)) * 8)]; \
  }                                                                       \
  _Pragma("unroll") for (int nt = 0; nt < 4; nt++) {                      \
    int n = wc + nt * 16 + l15;                                           \
    int R = n >> 1;                                                       \
    bv[nt] = *(const bf16x8*)&(BP)[R * 64 + (((quad | (hn << 2)) ^ (R & 7)) * 8)]; \
  }

#define MFMA16                                                            \
  __builtin_amdgcn_s_setprio(1);                                          \
  _Pragma("unroll") for (int mt = 0; mt < 4; mt++)                        \
  _Pragma("unroll") for (int nt = 0; nt < 4; nt++)                        \
    acc[mt][nt] = __builtin_amdgcn_mfma_f32_16x16x32_bf16(av[mt], bv[nt], acc[mt][nt], 0, 0, 0); \
  __builtin_amdgcn_s_setprio(0)

#define BAR __builtin_amdgcn_s_barrier()
#define LGKM0 asm volatile("s_waitcnt lgkmcnt(0)" ::: "memory")
#define VMC(N) asm volatile("s_waitcnt vmcnt(" #N ")" ::: "memory")

  // prologue: tile 0 -> buf0
  STG32(Ag, A0);
  STG32(Bg, B0);

  #pragma unroll
  for (int tp = 0; tp < 8; ++tp) {
    // even iter (tile 2tp in buf0): stage tile 2tp+1 -> buf1
    {
      STG32(Ag + (2 * tp + 1) * 32, A1);
      STG32(Bg + (2 * tp + 1) * 32, B1);
      VMC(4);  // drain tile-2tp's 4 loads; keep the 4 just issued in flight
      BAR;
      bf16x8 av[4], bv[4];
      FRAGS(A0, B0);
      LGKM0;
      MFMA16;
      BAR;
    }
    // odd iter (tile 2tp+1 in buf1): stage tile 2tp+2 -> buf0
    {
      if (tp < 7) {
        STG32(Ag + (2 * tp + 2) * 32, A0);
        STG32(Bg + (2 * tp + 2) * 32, B0);
        VMC(4);
      } else {
        VMC(0);
      }
      BAR;
      bf16x8 av[4], bv[4];
      FRAGS(A1, B1);
      LGKM0;
      MFMA16;
      BAR;
    }
  }

  // ---- epilogue (transplanted from the verified 128x128 kernel; s = blockIdx.y now) ----
  __syncthreads();
  {
    ushort* epi = (ushort*)sm;
    const float sc = (m0 < EMB) ? 0.125f : 1.0f;
    const int q4r = quad * 4;
    #pragma unroll
    for (int mt = 0; mt < 4; mt++) {
      int mb = wr + mt * 16 + q4r;
      float b0 = bias[m0 + mb], b1 = bias[m0 + mb + 1];
      float b2 = bias[m0 + mb + 2], b3 = bias[m0 + mb + 3];
      #pragma unroll
      for (int nt = 0; nt < 4; nt++) {
        int l = wc + nt * 16 + l15;
        unsigned u0 = f2bf((acc[mt][nt][0] + b0) * sc);
        unsigned u1 = f2bf((acc[mt][nt][1] + b1) * sc);
        unsigned u2 = f2bf((acc[mt][nt][2] + b2) * sc);
        unsigned u3 = f2bf((acc[mt][nt][3] + b3) * sc);
        uint2 pk;
        pk.x = u0 | (u1 << 16);
        pk.y = u2 | (u3 << 16);
        *(uint2*)&epi[l * 136 + mb] = pk;
      }
    }
  }
  __syncthreads();
  {
    const ushort* epi = (const ushort*)sm;
    const int sel = m0 >> 9;
    const int hb = (m0 & 511) >> 6;
    const int s = blockIdx.y;
    #pragma unroll
    for (int it = 0; it < 8; it++) {
      int flat = it * 2048 + tid * 8;
      int head = flat >> 13;
      int rem = flat & 8191;
      int l = rem >> 6;
      int dd = rem & 63;
      size_t dst = ((((size_t)(b * 3 + sel) * 8 + hb + head) * 128 + s) * 128 + l) * 64 + dd;
      *(uint4*)&rowQ[dst] = *(const uint4*)&epi[l * 136 + head * 64 + dd];
    }
  }
#undef STG32
#undef FRAGS
#undef MFMA16
#undef BAR
#undef LGKM0
#undef VMC
}

// ---------------- barrier-light MFMA axial attention ----------------
// COL=1: block=(l,h,b), queries over s. Writes tmp [b][h][l][s][d] bf16.
// COL=0: block=(s,h,b), queries over l. Adds tmp, writes out fp32 (O^T via swapped MFMA operands).
// LDS: Ks 16K (async, xor-swizzled) + Vt 17K + Ps 17K = 50 KB -> 3 blocks/CU. ONE __syncthreads.
template <int COL>
__global__ __launch_bounds__(256) void attn3(const ushort* __restrict__ qkv,
                                             ushort* __restrict__ tmp,
                                             float* __restrict__ out) {
  __shared__ ushort Ks[128 * 64];   // [t][64d], chunk-xor-swizzled
  __shared__ ushort Vt[64 * 136];   // [d][128t pad8]
  __shared__ ushort Ps[64 * 136];   // [q][128t pad8], wave-private rows
  const int tid = threadIdx.x;
  const int fixed = blockIdx.x;
  const int h = blockIdx.y, b = blockIdx.z;
  const int w = tid >> 6, lane = tid & 63, l15 = lane & 15, quad = lane >> 4;
  const size_t off = COL ? (size_t)fixed * 64 : (size_t)fixed * 8192;
  const size_t tstr = COL ? 8192 : 64;
  const ushort* Qg = qkv + ((size_t)(b * 3 + 0) * 8 + h) * 1048576 + off;
  const ushort* Kg = Qg + (size_t)8 * 1048576;
  const ushort* Vg = Qg + (size_t)16 * 1048576;
  ushort* tb = tmp + (size_t)(b * 8 + h) * 1048576;
  // ---- K: async global->LDS, xor chunk swizzle ----
  {
    int r8k = lane >> 3;
    int cgk = (lane & 7) ^ r8k;
    #pragma unroll
    for (int t = 0; t < 4; t++) {
      int seg = 4 * w + t;
      int row = seg * 8 + r8k;
      async16(&Kg[(size_t)row * tstr + cgk * 8], &Ks[seg * 512]);
    }
  }
  // ---- V: manual transposed stage (rotated scatter, conflict-free) ----
  {
    int trow = tid >> 3, d0 = (tid & 7) * 8, dg = tid & 7;
    #pragma unroll
    for (int it = 0; it < 4; it++) {
      int t = trow + it * 32;
      uint4 vv = *(const uint4*)&Vg[(size_t)t * tstr + d0];
      ushort* vs = (ushort*)&vv;
      #pragma unroll
      for (int k = 0; k < 8; k++) {
        int i = (k + dg) & 7;
        Vt[(d0 + i) * 136 + t] = vs[i];
      }
    }
  }
  // ---- Q fragments (wave-private): direct global->reg, both chunks ----
  bf16x8 aq[2][2];
  #pragma unroll
  for (int c = 0; c < 2; c++) {
    const ushort* qp = Qg + (size_t)(c * 64 + w * 16 + l15) * tstr + quad * 8;
    aq[c][0] = *(const bf16x8*)qp;
    aq[c][1] = *(const bf16x8*)(qp + 32);
  }
  // ---- row pass: prefetch col-pass partials (lane q = w*16+l15, d = mt*16+quad*4..+3) ----
  uint2 treg[2][4];
  if (!COL) {
    #pragma unroll
    for (int c = 0; c < 2; c++) {
      const ushort* tp = tb + (size_t)(c * 64 + w * 16 + l15) * 8192 + (size_t)fixed * 64 + quad * 4;
      #pragma unroll
      for (int mt = 0; mt < 4; mt++) treg[c][mt] = *(const uint2*)(tp + mt * 16);
    }
  }
  __syncthreads();  // the ONLY block barrier
  const int rx = l15 & 7;
  #pragma unroll
  for (int c = 0; c < 2; c++) {
    // ---- S = Q K^T ----
    f32x4 accS[8];
    #pragma unroll
    for (int nt = 0; nt < 8; nt++) {
      int row = nt * 16 + l15;
      bf16x8 bk0 = *(const bf16x8*)&Ks[row * 64 + ((quad ^ rx) * 8)];
      bf16x8 bk1 = *(const bf16x8*)&Ks[row * 64 + (((quad + 4) ^ rx) * 8)];
      f32x4 z = {0.f, 0.f, 0.f, 0.f};
      z = __builtin_amdgcn_mfma_f32_16x16x32_bf16(aq[c][0], bk0, z, 0, 0, 0);
      z = __builtin_amdgcn_mfma_f32_16x16x32_bf16(aq[c][1], bk1, z, 0, 0, 0);
      accS[nt] = z;
    }
    // ---- softmax over t; fold 1/l into P ----
    float inv[4];
    #pragma unroll
    for (int r = 0; r < 4; r++) {
      float mx = accS[0][r];
      #pragma unroll
      for (int nt = 1; nt < 8; nt++) mx = fmaxf(mx, accS[nt][r]);
      mx = fmaxf(mx, __shfl_xor(mx, 1));
      mx = fmaxf(mx, __shfl_xor(mx, 2));
      mx = fmaxf(mx, __shfl_xor(mx, 4));
      mx = fmaxf(mx, __shfl_xor(mx, 8));
      float s = 0.f;
      #pragma unroll
      for (int nt = 0; nt < 8; nt++) {
        float p = __builtin_amdgcn_exp2f((accS[nt][r] - mx) * 1.44269504088896f);
        accS[nt][r] = p;
        s += p;
      }
      s += __shfl_xor(s, 1);
      s += __shfl_xor(s, 2);
      s += __shfl_xor(s, 4);
      s += __shfl_xor(s, 8);
      inv[r] = 1.0f / s;
    }
    // ---- P -> LDS (wave-private rows; wave-level ordering only) ----
    asm volatile("s_waitcnt lgkmcnt(0)" ::: "memory");  // prior chunk's Ps reads retired
    #pragma unroll
    for (int nt = 0; nt < 8; nt++)
      #pragma unroll
      for (int r = 0; r < 4; r++)
        Ps[(w * 16 + quad * 4 + r) * 136 + nt * 16 + l15] = f2bf(accS[nt][r] * inv[r]);
    asm volatile("s_waitcnt lgkmcnt(0)" ::: "memory");  // Ps writes visible to own wave
    // ---- O = P V  (COL: C[q][d])   or   O^T = V^T P^T  (ROW: C[d][q]) ----
    f32x4 accO[4] = {{0.f,0.f,0.f,0.f},{0.f,0.f,0.f,0.f},{0.f,0.f,0.f,0.f},{0.f,0.f,0.f,0.f}};
    #pragma unroll
    for (int kf = 0; kf < 4; kf++) {
      bf16x8 p = *(const bf16x8*)&Ps[(w * 16 + l15) * 136 + kf * 32 + quad * 8];
      #pragma unroll
      for (int t4 = 0; t4 < 4; t4++) {
        bf16x8 v = *(const bf16x8*)&Vt[(t4 * 16 + l15) * 136 + kf * 32 + quad * 8];
        accO[t4] = COL ? __builtin_amdgcn_mfma_f32_16x16x32_bf16(p, v, accO[t4], 0, 0, 0)
                       : __builtin_amdgcn_mfma_f32_16x16x32_bf16(v, p, accO[t4], 0, 0, 0);
      }
    }
    if (COL) {
      // lane holds (q = w*16+quad*4+r, d = t4*16+l15): 32 B-coalesced bf16 runs
      ushort* tp = tb + (size_t)fixed * 8192 + c * 4096;
      #pragma unroll
      for (int t4 = 0; t4 < 4; t4++)
        #pragma unroll
        for (int r = 0; r < 4; r++)
          tp[(w * 16 + quad * 4 + r) * 64 + t4 * 16 + l15] = f2bf(accO[t4][r]);
    } else {
      // lane holds (d = t4*16+quad*4+r, q = w*16+l15): 64 B-coalesced fp32 runs
      float* ob = out + (size_t)(b * EMB + h * 64) * SL + (size_t)fixed * 128 + c * 64 + w * 16 + l15;
      #pragma unroll
      for (int t4 = 0; t4 < 4; t4++) {
        const ushort* tr = (const ushort*)&treg[c][t4];
        #pragma unroll
        for (int r = 0; r < 4; r++)
          ob[(size_t)(t4 * 16 + quad * 4 + r) * SL] = accO[t4][r] + bf2f(tr[r]);
      }
    }
  }
}

extern "C" void kernel_launch(void* const* d_in, const int* in_sizes, int n_in,
                              void* d_out, int out_size, void* d_ws, size_t ws_size,
                              hipStream_t stream) {
  const float* x = (const float*)d_in[0];
  const float* W = (const float*)d_in[1];
  const float* bias = (const float*)d_in[2];
  float* out = (float*)d_out;
  ushort* rowQ = (ushort*)d_ws;
  ushort* xT = (ushort*)((char*)d_ws + 100663296);
  ushort* tmp = (ushort*)((char*)d_ws + 100663296);
  ushort* Wb = (ushort*)((char*)d_ws + 134217728);

  hipLaunchKernelGGL(wconv, dim3(768), dim3(256), 0, stream, W, Wb);
  hipLaunchKernelGGL(xpose, dim3(256, 8, 2), dim3(256), 0, stream, x, xT);
  hipLaunchKernelGGL(qkv_gemm, dim3(12, 128, 2), dim3(256), 0, stream, Wb, xT, bias, rowQ);
  hipLaunchKernelGGL(attn3<1>, dim3(128, 8, 2), dim3(256), 0, stream, rowQ, tmp, out);
  hipLaunchKernelGGL(attn3<0>, dim3(128, 8, 2), dim3(256), 0, stream, rowQ, tmp, out);
}